// Round 10
// baseline (38.799 us; speedup 1.0000x reference)
//
#include <hip/hip_runtime.h>
#include <hip/hip_bf16.h>

// Shapes (fixed): D=1, S=64, A=128, P=K=6, T=80
#define NS 64
#define NA 128
#define NK 6
#define NT 80

// Output layout (flat concat, float):
//   waymo_valid  [S,T,A]        655360
//   waymo_trajs  [S,T,A,K,2]    7864320
//   waymo_scores [S,A,K]        49152
//   waymo_yaw    [S,T,A,K,1]    3932160
#define OFF_TRAJ   655360
#define OFF_SCORE  (655360 + 7864320)
#define OFF_YAW    (655360 + 7864320 + 49152)

typedef float nfloat4 __attribute__((ext_vector_type(4)));

// ================= Kernel A: pos -> score/NMS + traj transpose =================
// TILE 4 agents (24 rows), LDS 15.7 KB, 256 thr -> 8 blocks/CU (wave-capped), grid 2048
#define APS 82   // float2 row stride

__global__ __launch_bounds__(256) void waymo_pos_kernel(
    const int*    __restrict__ validIn,
    const float*  __restrict__ confIn,
    const float2* __restrict__ posIn,
    const float*  __restrict__ typeIn,
    float*        __restrict__ out)
{
    const int s   = blockIdx.y;
    const int a0  = blockIdx.x * 4;
    const int tid = threadIdx.x;

    __shared__ float2 sP[24 * APS];   // 15744 B

    const size_t sa0 = (size_t)s * NA + a0;
    const float2* pbase = posIn + sa0 * (NK * NT);

    // stage: 24 rows x 40 f4 = 960 f4, contiguous 15 KB
    for (int i = tid; i < 960; i += 256) {
        int r = i / 40, q = i - r * 40;
        nfloat4 v = *(const nfloat4*)(pbase + (size_t)r * NT + 2 * q);
        *(nfloat4*)&sP[r * APS + 2 * q] = v;
    }
    __syncthreads();

    // score/NMS: waves 0..1, 32 lanes per agent (4 agents)
    if (tid < 128) {
        const int la   = tid >> 5;
        const int lane = tid & 31;
        const int p    = lane >> 1;
        const int half = lane & 1;

        const size_t sa = (size_t)s * NA + a0 + la;
        const float th = 2.5f * typeIn[sa * 3 + 0]
                       + 1.0f * typeIn[sa * 3 + 1]
                       + 1.5f * typeIn[sa * 3 + 2];

        int pi, pj;
        if      (p < 5)  { pi = 0; pj = p + 1; }
        else if (p < 9)  { pi = 1; pj = p - 3; }
        else if (p < 12) { pi = 2; pj = p - 6; }
        else if (p < 14) { pi = 3; pj = p - 8; }
        else             { pi = 4; pj = 5;     }

        const int rI = la * NK + pi, rJ = la * NK + pj;
        float dsum = 0.f;
        for (int t = half * 40; t < half * 40 + 40; ++t) {
            float2 u = sP[rI * APS + t];
            float2 v = sP[rJ * APS + t];
            float dx = u.x - v.x, dy = u.y - v.y;
            dsum += sqrtf(dx * dx + dy * dy);
        }
        dsum += __shfl_xor(dsum, 1);
        const bool within = (dsum / 80.0f) < th;
        const bool predb  = (half == 0) && (p < 15) && within;
        unsigned long long bal = __ballot(predb);
        unsigned mask32 = (unsigned)(bal >> (tid & 32));

        if (lane == 0) {
            float c[NK];
            float mx = -3e38f;
            for (int q = 0; q < NK; ++q) { c[q] = confIn[sa * NK + q]; mx = fmaxf(mx, c[q]); }
            float ssum = 0.f;
            for (int q = 0; q < NK; ++q) { c[q] = expf(c[q] - mx); ssum += c[q]; }
            for (int q = 0; q < NK; ++q) c[q] /= ssum;
            ssum = 0.f;
            for (int q = 0; q < NK; ++q) ssum += c[q];
            for (int q = 0; q < NK; ++q) c[q] /= ssum;

            int ord[NK]; bool used[NK];
            for (int q = 0; q < NK; ++q) used[q] = false;
            for (int st = 0; st < NK; ++st) {
                int best = 0; float bv = -3e38f;
                for (int q = 0; q < NK; ++q)
                    if (!used[q] && c[q] > bv) { bv = c[q]; best = q; }
                used[best] = true; ord[st] = best;
            }

            float cur[NK];
            for (int q = 0; q < NK; ++q) cur[q] = c[q];

            if (validIn[sa] != 0) {
                for (int st = 0; st < NK; ++st) {
                    int k = ord[st];
                    float ck = cur[k];
                    bool any = false;
                    for (int j = 0; j < NK; ++j) {
                        if (j == k) continue;
                        int lo = j < k ? j : k;
                        int hi = j < k ? k : j;
                        int pidx = lo * 5 - (lo * (lo - 1)) / 2 + (hi - lo - 1);
                        if (((mask32 >> (2 * pidx)) & 1u) && (cur[j] > ck)) any = true;
                    }
                    if (any) cur[k] = 0.001f;
                }
            }

            float tsum = 0.f;
            for (int q = 0; q < NK; ++q) tsum += cur[q];
            float w[NK]; float wsum = 0.f;
            for (int q = 0; q < NK; ++q) {
                float qq = cur[q] / tsum;
                w[q] = qq * qq; wsum += w[q];
            }
            float* outSc = out + OFF_SCORE;
            for (int q = 0; q < NK; ++q) outSc[sa * NK + q] = w[q] / wsum;
        }
    }

    // traj out: per t, 24 f2 rows -> 12 f4 (192B runs, 192B-aligned); 960 f4
    nfloat4* trajOut = (nfloat4*)(out + OFF_TRAJ);
    for (int o = tid; o < 960; o += 256) {
        int t = o / 12, j = o - (o / 12) * 12;
        float2 u = sP[(2 * j + 0) * APS + t];
        float2 w = sP[(2 * j + 1) * APS + t];
        nfloat4 v{u.x, u.y, w.x, w.y};
        size_t f4 = (size_t)(s * NT + t) * 384 + a0 * 3 + j;
        trajOut[f4] = v;
    }
}

// ================= Kernel B: yaw transpose =================
// TILE 8 agents (48 rows), LDS 16.1 KB, 256 thr, grid 1024
#define BYS 84   // float row stride

__global__ __launch_bounds__(256) void waymo_yaw_kernel(
    const float* __restrict__ yawIn,
    float*       __restrict__ out)
{
    const int s   = blockIdx.y;
    const int a0  = blockIdx.x * 8;
    const int tid = threadIdx.x;

    __shared__ float sY[48 * BYS];   // 16128 B

    const size_t sa0 = (size_t)s * NA + a0;
    const float* ybase = yawIn + sa0 * (NK * NT);

    // stage: 48 rows x 20 f4 = 960 f4, contiguous 15 KB
    for (int i = tid; i < 960; i += 256) {
        int r = i / 20, m = i - r * 20;
        nfloat4 v = *(const nfloat4*)(ybase + (size_t)r * NT + 4 * m);
        *(nfloat4*)&sY[r * BYS + 4 * m] = v;
    }
    __syncthreads();

    // yaw out: per t, 48 floats -> 12 f4 (192B runs, 192B-aligned); 960 f4
    nfloat4* yawOut = (nfloat4*)(out + OFF_YAW);
    for (int o = tid; o < 960; o += 256) {
        int t = o / 12, j = o - (o / 12) * 12;
        nfloat4 v{sY[(4 * j + 0) * BYS + t],
                  sY[(4 * j + 1) * BYS + t],
                  sY[(4 * j + 2) * BYS + t],
                  sY[(4 * j + 3) * BYS + t]};
        size_t f4 = (size_t)(s * NT + t) * 192 + ((a0 * 6) >> 2) + j;
        yawOut[f4] = v;
    }
}

// ================= Kernel C: valid broadcast =================
// one block per scene; 40 KB fully-contiguous stores per block
__global__ __launch_bounds__(256) void waymo_valid_kernel(
    const int* __restrict__ validIn,
    float*     __restrict__ out)
{
    const int s   = blockIdx.x;
    const int tid = threadIdx.x;

    __shared__ nfloat4 vrow[NA / 4];   // 128 agents as 32 f4

    if (tid < 32) {
        const int b = (int)((size_t)s * NA) + 4 * tid;
        nfloat4 v;
        v.x = (validIn[b + 0] != 0) ? 1.0f : 0.0f;
        v.y = (validIn[b + 1] != 0) ? 1.0f : 0.0f;
        v.z = (validIn[b + 2] != 0) ? 1.0f : 0.0f;
        v.w = (validIn[b + 3] != 0) ? 1.0f : 0.0f;
        vrow[tid] = v;
    }
    __syncthreads();

    nfloat4* vOut = (nfloat4*)out;
    for (int o = tid; o < NT * 32; o += 256) {
        int t = o >> 5, q = o & 31;
        vOut[(size_t)(s * NT + t) * 32 + q] = vrow[q];
    }
}

extern "C" void kernel_launch(void* const* d_in, const int* in_sizes, int n_in,
                              void* d_out, int out_size, void* d_ws, size_t ws_size,
                              hipStream_t stream) {
    const int*    validIn = (const int*)d_in[0];
    const float*  confIn  = (const float*)d_in[1];
    const float2* posIn   = (const float2*)d_in[2];
    const float*  yawIn   = (const float*)d_in[3];
    const float*  typeIn  = (const float*)d_in[4];
    float* out = (float*)d_out;

    dim3 gridA(NA / 4, NS);   // 2048 blocks
    waymo_pos_kernel<<<gridA, 256, 0, stream>>>(validIn, confIn, posIn, typeIn, out);
    dim3 gridB(NA / 8, NS);   // 1024 blocks
    waymo_yaw_kernel<<<gridB, 256, 0, stream>>>(yawIn, out);
    waymo_valid_kernel<<<NS, 256, 0, stream>>>(validIn, out);
}